// Round 9
// baseline (204.174 us; speedup 1.0000x reference)
//
#include <hip/hip_runtime.h>

#define NSRC 20000
#define NDST 20000
#define NTOT 40000
#define ETOT 320000
#define ENEG 316800
#define NH 8
#define ND 16
#define NHD 128
#define BCAP 64  // fixed bucket capacity per dst (Poisson(16): P(>63) ~ 1e-20)

typedef __bf16 v8bf __attribute__((ext_vector_type(8)));
typedef float v4f __attribute__((ext_vector_type(4)));

// ---------------- workspace layout (bytes) ----------------
// [0, 40000)           negbits (10000 u32)      } zeroed
// [40000, 120000)      cursor/deg (20000 int)   } zeroed -> zero region 120000 B
// [120064, 5240064)    csr buckets (20000 x 64 int; bit31 = in-neg-set)
// [5240064, 5320064)   expcos (20000 f32)
// [5320064, 15560064)  z (40000 x 128 bf16)
// [15560064, 16840064) el (40000 x 8 f32)
// [16840064, 18120064) er (40000 x 8 f32)
// [18120064, 18152832) bt (128 x 128 bf16 = fc_w transposed)

// prep: blocks 0..63 transpose fc_w -> bt (bf16, [n][k]); blocks 64..191
// fill the neg-edge bitmask. Both tiny, fully parallel.
__global__ __launch_bounds__(256) void k_prep(const float* __restrict__ B,
                                              const int* __restrict__ neg_idx,
                                              unsigned short* __restrict__ bt,
                                              unsigned int* __restrict__ negbits) {
    const int bid = blockIdx.x;
    if (bid < 64) {  // coalesced read of B, scattered 2B write of bt
        int i = bid * 256 + threadIdx.x;  // 0..16383
        int k = i >> 7, n = i & 127;
        unsigned int u = __float_as_uint(B[i]);
        unsigned int b = (u + 0x7fffu + ((u >> 16) & 1u)) >> 16;  // RNE
        bt[n * 128 + k] = (unsigned short)b;
    } else {
        int t0 = (bid - 64) * 256 + threadIdx.x;  // 0..32767
        for (int i = t0; i < ENEG; i += 32768) {
            int e = neg_idx[i];
            atomicOr(&negbits[e >> 5], 1u << (e & 31));
        }
    }
}

// MFMA bf16 GEMM z = feat @ fc_w + fused el/er epilogue. NO LDS: B-fragments
// load straight from bt (32 KB, L1/L2-resident) as 16B v8bf; A-fragments from
// feat rows. Grid 625 x 256 (wave w covers rows bid*64+w*16..+15).
__global__ __launch_bounds__(256) void k_front(const float* __restrict__ A,
                                               const unsigned short* __restrict__ bt,
                                               const float* __restrict__ attn_l,
                                               const float* __restrict__ attn_r,
                                               unsigned short* __restrict__ z,
                                               float* __restrict__ el,
                                               float* __restrict__ er) {
    const int tid = threadIdx.x;
    const int bid = blockIdx.x;
    const int w = tid >> 6, lane = tid & 63;
    const int ml = lane & 15, q = lane >> 4;
    const int gm = bid * 64 + w * 16 + ml;  // this lane's A row (m = lane&15)
    v4f acc[8];
#pragma unroll
    for (int n = 0; n < 8; ++n) acc[n] = (v4f){0.f, 0.f, 0.f, 0.f};
#pragma unroll
    for (int ks = 0; ks < 4; ++ks) {
        const int k0 = ks * 32 + q * 8;  // A[m][k]: k = quad*8 + j
        float4 f0 = *(const float4*)(A + (size_t)gm * 128 + k0);
        float4 f1 = *(const float4*)(A + (size_t)gm * 128 + k0 + 4);
        v8bf av;
        av[0] = (__bf16)f0.x; av[1] = (__bf16)f0.y;
        av[2] = (__bf16)f0.z; av[3] = (__bf16)f0.w;
        av[4] = (__bf16)f1.x; av[5] = (__bf16)f1.y;
        av[6] = (__bf16)f1.z; av[7] = (__bf16)f1.w;
#pragma unroll
        for (int n = 0; n < 8; ++n) {
            v8bf bv = *(const v8bf*)(bt + (size_t)(n * 16 + ml) * 128 + k0);
            acc[n] = __builtin_amdgcn_mfma_f32_16x16x32_bf16(av, bv, acc[n], 0, 0, 0);
        }
    }
    // ---- epilogue: z store (bf16 RNE) + el/er from fp32 accumulators ----
    // C layout: row = q*4 + reg, col = n*16 + ml  (head = n)
    const int rowbase = bid * 64 + w * 16 + q * 4;
#pragma unroll
    for (int n = 0; n < 8; ++n) {
        float alv = attn_l[n * 16 + ml];
        float arv = attn_r[n * 16 + ml];
#pragma unroll
        for (int r = 0; r < 4; ++r) {
            float v = acc[n][r];
            unsigned int u = __float_as_uint(v);
            unsigned int b = (u + 0x7fffu + ((u >> 16) & 1u)) >> 16;  // RNE
            z[(size_t)(rowbase + r) * NHD + n * 16 + ml] = (unsigned short)b;
            float pl = v * alv, pr = v * arv;
#pragma unroll
            for (int s = 1; s <= 8; s <<= 1) {  // reduce 16 cols (lane bits 0..3)
                pl += __shfl_xor(pl, s, 64);
                pr += __shfl_xor(pr, s, 64);
            }
            if (ml == 0) {
                el[(rowbase + r) * NH + n] = pl;
                er[(rowbase + r) * NH + n] = pr;
            }
        }
    }
}

// bucket scatter: slot within dst from atomicAdd(cursor); neg membership
// from the 40 KB bitmask (L2-resident).
__global__ __launch_bounds__(256) void k_scatter(const int* __restrict__ edge_src,
                                                 const int* __restrict__ edge_dst,
                                                 const unsigned int* __restrict__ negbits,
                                                 int* __restrict__ cursor,
                                                 int* __restrict__ csr) {
    int i = blockIdx.x * 256 + threadIdx.x;
    if (i >= ETOT) return;
    int d = edge_dst[i] - NSRC;
    int slot = atomicAdd(&cursor[d], 1);
    int v = edge_src[i];
    if ((negbits[i >> 5] >> (i & 31)) & 1u) v |= (int)0x80000000u;
    if (slot < BCAP) csr[d * BCAP + slot] = v;
}

// One wave per dst node, chunk = 16 edges, zero LDS, bf16 z, shared-max
// softmax (neg graph ⊂ full graph, shift invariance -> one running max).
// PROVEN-GOOD STRUCTURE. Allocator-fragile: the speed depends on one flat
// batch of 16 independent loads staying in VGPRs. DO NOT: enlarge the batch
// (r6: 237 µs), branch inside the chunk body (r6), or add LDS/barriers/
// atomics to this kernel (r3: 195 µs).
__global__ __launch_bounds__(256) void k_agg(const int* __restrict__ degarr,
                                             const int* __restrict__ csr,
                                             const unsigned short* __restrict__ z,
                                             const float* __restrict__ el,
                                             const float* __restrict__ er,
                                             const float* __restrict__ bias,
                                             const float* __restrict__ prelu_a,
                                             float* __restrict__ out,
                                             float* __restrict__ expcos) {
    const int lane = threadIdx.x & 63;
    const int wid = threadIdx.x >> 6;
    const int d = (blockIdx.x << 2) + wid;  // grid = NDST/4 exactly

    const int g = NSRC + d;
    const int hl = lane >> 3;
    const int j8 = lane & 7;
    const int rs = d * BCAP;
    const int deg = degarr[d];
    const float erd = er[g * NH + hl];
    const float aslope = prelu_a[0];
    const float NEGINF = -__builtin_inff();

    float mF = NEGINF, lF = 0.f, lN = 0.f;
    float aF0 = 0.f, aF1 = 0.f, aN0 = 0.f, aN1 = 0.f;

    for (int base = 0; base < deg; base += 16) {
        const int j0 = base + j8, j1 = base + 8 + j8;
        int ent0 = (j0 < deg) ? csr[rs + j0] : g;
        int ent1 = (j1 < deg) ? csr[rs + j1] : g;
        unsigned int zr[16];  // bf16x2 per lane per edge-row
#pragma unroll
        for (int jj = 0; jj < 16; ++jj) {
            int entry = __shfl((jj < 8) ? ent0 : ent1, jj & 7, 64);
            zr[jj] = *(const unsigned int*)(z + ((size_t)(entry & 0x7FFFFFFF) << 7) + 2 * lane);
        }
        float e0 = el[(size_t)(ent0 & 0x7FFFFFFF) * NH + hl] + erd;
        float e1 = el[(size_t)(ent1 & 0x7FFFFFFF) * NH + hl] + erd;
        e0 = (e0 >= 0.f) ? e0 : 0.2f * e0;
        e1 = (e1 >= 0.f) ? e1 : 0.2f * e1;
        float ev0 = (j0 < deg) ? e0 : NEGINF;
        float ev1 = (j1 < deg) ? e1 : NEGINF;
        const int fl0 = (j0 < deg) && (ent0 < 0);
        const int fl1 = (j1 < deg) && (ent1 < 0);
        float cm = fmaxf(ev0, ev1);
#pragma unroll
        for (int s = 1; s <= 4; s <<= 1) cm = fmaxf(cm, __shfl_xor(cm, s, 64));
        float nm = fmaxf(mF, cm);
        float sc = (nm == mF) ? 1.f : __expf(mF - nm);
        mF = nm;
        float wf0 = __expf(ev0 - mF);  // 0 for pad slots (mF finite)
        float wf1 = __expf(ev1 - mF);
        lF = lF * sc + wf0 + wf1;
        lN = lN * sc + (fl0 ? wf0 : 0.f) + (fl1 ? wf1 : 0.f);
        float w0 = fl0 ? -wf0 : wf0;  // sign bit = neg-graph membership
        float w1 = fl1 ? -wf1 : wf1;
        aF0 *= sc; aF1 *= sc; aN0 *= sc; aN1 *= sc;
#pragma unroll
        for (int jj = 0; jj < 16; ++jj) {
            float v = __shfl((jj < 8) ? w0 : w1, (lane & 56) | (jj & 7), 64);
            float wf = fabsf(v);
            float wn = (v < 0.f) ? wf : 0.f;
            float zx = __uint_as_float(zr[jj] << 16);
            float zy = __uint_as_float(zr[jj] & 0xffff0000u);
            aF0 = fmaf(wf, zx, aF0);
            aF1 = fmaf(wf, zy, aF1);
            aN0 = fmaf(wn, zx, aN0);
            aN1 = fmaf(wn, zy, aN1);
        }
    }

    // self-loop (in both graphs, shares mF)
    {
        float e = el[g * NH + hl] + erd;
        e = (e >= 0.f) ? e : 0.2f * e;
        float nm = fmaxf(mF, e);
        float sc = (nm == mF) ? 1.f : __expf(mF - nm);
        lF *= sc; lN *= sc;
        aF0 *= sc; aF1 *= sc; aN0 *= sc; aN1 *= sc;
        mF = nm;
        float wf = __expf(e - mF);
        if (j8 == 0) { lF += wf; lN += wf; }  // denom: once per head group
        unsigned int zv = *(const unsigned int*)(z + ((size_t)g << 7) + 2 * lane);
        float zx = __uint_as_float(zv << 16);
        float zy = __uint_as_float(zv & 0xffff0000u);
        aF0 = fmaf(wf, zx, aF0);
        aF1 = fmaf(wf, zy, aF1);
        aN0 = fmaf(wf, zx, aN0);
        aN1 = fmaf(wf, zy, aN1);
    }

    // denominators per head group (reduce over j8 bits)
#pragma unroll
    for (int s = 1; s <= 4; s <<= 1) {
        lF += __shfl_xor(lF, s, 64);
        lN += __shfl_xor(lN, s, 64);
    }
    const int c0 = 2 * lane;
    float b0 = bias[c0], b1 = bias[c0 + 1];
    float rF0 = aF0 / lF + b0, rF1 = aF1 / lF + b1;
    float rN0 = aN0 / lN + b0, rN1 = aN1 / lN + b1;
    rF0 = (rF0 >= 0.f) ? rF0 : aslope * rF0;
    rF1 = (rF1 >= 0.f) ? rF1 : aslope * rF1;
    rN0 = (rN0 >= 0.f) ? rN0 : aslope * rN0;
    rN1 = (rN1 >= 0.f) ? rN1 : aslope * rN1;
    // head mean: sum over heads (bits 3..5), /8
#pragma unroll
    for (int s = 8; s <= 32; s <<= 1) {
        rF0 += __shfl_xor(rF0, s, 64);
        rF1 += __shfl_xor(rF1, s, 64);
        rN0 += __shfl_xor(rN0, s, 64);
        rN1 += __shfl_xor(rN1, s, 64);
    }
    float hF0 = rF0 * 0.125f, hF1 = rF1 * 0.125f;
    float hN0 = rN0 * 0.125f, hN1 = rN1 * 0.125f;
    if (lane < 8) {
        out[1 + d * ND + 2 * lane] = hF0;
        out[1 + d * ND + 2 * lane + 1] = hF1;
    }
    float num = hF0 * hN0 + hF1 * hN1;
    float na = hF0 * hF0 + hF1 * hF1;
    float nb = hN0 * hN0 + hN1 * hN1;
#pragma unroll
    for (int s = 1; s <= 4; s <<= 1) {
        num += __shfl_xor(num, s, 64);
        na += __shfl_xor(na, s, 64);
        nb += __shfl_xor(nb, s, 64);
    }
    if (lane == 0) {
        float cosv = num / (fmaxf(sqrtf(na), 1e-8f) * fmaxf(sqrtf(nb), 1e-8f));
        expcos[d] = __expf(cosv / 0.7f);
    }
}

__global__ __launch_bounds__(1024) void k_loss(const float* __restrict__ expcos,
                                               float* __restrict__ out) {
    __shared__ float sbuf[16];
    float s = 0.f;
    for (int i = threadIdx.x; i < NDST; i += 1024) s += expcos[i];
    for (int sh = 1; sh < 64; sh <<= 1) s += __shfl_xor(s, sh, 64);
    if ((threadIdx.x & 63) == 0) sbuf[threadIdx.x >> 6] = s;
    __syncthreads();
    if (threadIdx.x < 16) {
        float t = sbuf[threadIdx.x];
        for (int sh = 1; sh < 16; sh <<= 1) t += __shfl_xor(t, sh, 16);
        if (threadIdx.x == 0) out[0] = logf(t);
    }
}

extern "C" void kernel_launch(void* const* d_in, const int* in_sizes, int n_in,
                              void* d_out, int out_size, void* d_ws, size_t ws_size,
                              hipStream_t stream) {
    const float* feat = (const float*)d_in[0];
    const float* fc_w = (const float*)d_in[1];
    const float* attn_l = (const float*)d_in[2];
    const float* attn_r = (const float*)d_in[3];
    const float* bias = (const float*)d_in[4];
    const float* prelu_a = (const float*)d_in[5];
    const int* edge_src = (const int*)d_in[6];
    const int* edge_dst = (const int*)d_in[7];
    const int* neg_idx = (const int*)d_in[8];
    float* out = (float*)d_out;

    char* ws = (char*)d_ws;
    unsigned int* negbits = (unsigned int*)(ws + 0);
    int* cursor = (int*)(ws + 40000);
    int* csr = (int*)(ws + 120064);
    float* expcos = (float*)(ws + 5240064);
    unsigned short* z = (unsigned short*)(ws + 5320064);
    float* el = (float*)(ws + 15560064);
    float* er = (float*)(ws + 16840064);
    unsigned short* bt = (unsigned short*)(ws + 18120064);

    hipMemsetAsync(d_ws, 0, 120000, stream);  // negbits + cursor
    k_prep<<<192, 256, 0, stream>>>(fc_w, neg_idx, bt, negbits);
    k_front<<<625, 256, 0, stream>>>(feat, bt, attn_l, attn_r, z, el, er);
    k_scatter<<<(ETOT + 255) / 256, 256, 0, stream>>>(edge_src, edge_dst,
                                                      negbits, cursor, csr);
    k_agg<<<NDST / 4, 256, 0, stream>>>(cursor, csr, z, el, er, bias, prelu_a,
                                        out, expcos);
    k_loss<<<1, 1024, 0, stream>>>(expcos, out);
}

// Round 10
// 161.504 us; speedup vs baseline: 1.2642x; 1.2642x over previous
//
#include <hip/hip_runtime.h>

#define NSRC 20000
#define NDST 20000
#define NTOT 40000
#define ETOT 320000
#define ENEG 316800
#define NH 8
#define ND 16
#define NHD 128
#define BCAP 64  // fixed bucket capacity per dst (Poisson(16): P(>63) ~ 1e-20)

typedef __bf16 v8bf __attribute__((ext_vector_type(8)));
typedef float v4f __attribute__((ext_vector_type(4)));

// ---------------- workspace layout (bytes) ----------------
// [0, 80000)           cursor/deg (20000 int)   } memset 0
// [80000, 120000)      negbits (10000 u32)      } memset 0xFF (complement-clear)
// [120064, 5240064)    csr buckets (20000 x 64 int; bit31 = in-neg-set)
// [5240064, 5320064)   expcos (20000 f32)
// [5320064, 15560064)  z (40000 x 128 bf16)
// [15560064, 16840064) el (40000 x 8 f32)
// [16840064, 18120064) er (40000 x 8 f32)
// [18120064, 18152832) bt (128 x 128 bf16 = fc_w transposed)

// prep: blocks 0..63 transpose fc_w -> bt (bf16 [n][k]); blocks 64..1301
// clear the ~3200 complement bits of the neg-edge mask. neg_idx is SORTED
// and 99% dense -> atomicOr per member serializes on same-word RMWs
// (r9: 50 µs); clearing the gaps needs only ~3200 scattered atomicAnd.
__global__ __launch_bounds__(256) void k_prep(const float* __restrict__ B,
                                              const int* __restrict__ neg_idx,
                                              unsigned short* __restrict__ bt,
                                              unsigned int* __restrict__ negbits) {
    const int bid = blockIdx.x;
    if (bid < 64) {  // coalesced read of B, scattered 2B write of bt
        int i = bid * 256 + threadIdx.x;  // 0..16383
        int k = i >> 7, n = i & 127;
        unsigned int u = __float_as_uint(B[i]);
        unsigned int b = (u + 0x7fffu + ((u >> 16) & 1u)) >> 16;  // RNE
        bt[n * 128 + k] = (unsigned short)b;
        return;
    }
    int i = (bid - 64) * 256 + threadIdx.x;  // 0..ENEG
    if (i > ENEG) return;
    int a = (i == 0) ? -1 : neg_idx[i - 1];
    int b = (i == ENEG) ? ETOT : neg_idx[i];
    for (int e = a + 1; e < b; ++e)  // ids NOT in the neg set (total ~3200)
        atomicAnd(&negbits[e >> 5], ~(1u << (e & 31)));
}

// MFMA bf16 GEMM z = feat @ fc_w + fused el/er epilogue. NO LDS: B-fragments
// load straight from bt (32 KB, L1/L2-resident) as 16B v8bf; A-fragments from
// feat rows. Grid 625 x 256 (wave w covers rows bid*64+w*16..+15).
__global__ __launch_bounds__(256) void k_front(const float* __restrict__ A,
                                               const unsigned short* __restrict__ bt,
                                               const float* __restrict__ attn_l,
                                               const float* __restrict__ attn_r,
                                               unsigned short* __restrict__ z,
                                               float* __restrict__ el,
                                               float* __restrict__ er) {
    const int tid = threadIdx.x;
    const int bid = blockIdx.x;
    const int w = tid >> 6, lane = tid & 63;
    const int ml = lane & 15, q = lane >> 4;
    const int gm = bid * 64 + w * 16 + ml;  // this lane's A row (m = lane&15)
    v4f acc[8];
#pragma unroll
    for (int n = 0; n < 8; ++n) acc[n] = (v4f){0.f, 0.f, 0.f, 0.f};
#pragma unroll
    for (int ks = 0; ks < 4; ++ks) {
        const int k0 = ks * 32 + q * 8;  // A[m][k]: k = quad*8 + j
        float4 f0 = *(const float4*)(A + (size_t)gm * 128 + k0);
        float4 f1 = *(const float4*)(A + (size_t)gm * 128 + k0 + 4);
        v8bf av;
        av[0] = (__bf16)f0.x; av[1] = (__bf16)f0.y;
        av[2] = (__bf16)f0.z; av[3] = (__bf16)f0.w;
        av[4] = (__bf16)f1.x; av[5] = (__bf16)f1.y;
        av[6] = (__bf16)f1.z; av[7] = (__bf16)f1.w;
#pragma unroll
        for (int n = 0; n < 8; ++n) {
            v8bf bv = *(const v8bf*)(bt + (size_t)(n * 16 + ml) * 128 + k0);
            acc[n] = __builtin_amdgcn_mfma_f32_16x16x32_bf16(av, bv, acc[n], 0, 0, 0);
        }
    }
    // ---- epilogue: z store (bf16 RNE) + el/er from fp32 accumulators ----
    // C layout: row = q*4 + reg, col = n*16 + ml  (head = n)
    const int rowbase = bid * 64 + w * 16 + q * 4;
#pragma unroll
    for (int n = 0; n < 8; ++n) {
        float alv = attn_l[n * 16 + ml];
        float arv = attn_r[n * 16 + ml];
#pragma unroll
        for (int r = 0; r < 4; ++r) {
            float v = acc[n][r];
            unsigned int u = __float_as_uint(v);
            unsigned int b = (u + 0x7fffu + ((u >> 16) & 1u)) >> 16;  // RNE
            z[(size_t)(rowbase + r) * NHD + n * 16 + ml] = (unsigned short)b;
            float pl = v * alv, pr = v * arv;
#pragma unroll
            for (int s = 1; s <= 8; s <<= 1) {  // reduce 16 cols (lane bits 0..3)
                pl += __shfl_xor(pl, s, 64);
                pr += __shfl_xor(pr, s, 64);
            }
            if (ml == 0) {
                el[(rowbase + r) * NH + n] = pl;
                er[(rowbase + r) * NH + n] = pr;
            }
        }
    }
}

// bucket scatter: slot within dst from atomicAdd(cursor); neg membership
// from the 40 KB bitmask (L2-resident).
__global__ __launch_bounds__(256) void k_scatter(const int* __restrict__ edge_src,
                                                 const int* __restrict__ edge_dst,
                                                 const unsigned int* __restrict__ negbits,
                                                 int* __restrict__ cursor,
                                                 int* __restrict__ csr) {
    int i = blockIdx.x * 256 + threadIdx.x;
    if (i >= ETOT) return;
    int d = edge_dst[i] - NSRC;
    int slot = atomicAdd(&cursor[d], 1);
    int v = edge_src[i];
    if ((negbits[i >> 5] >> (i & 31)) & 1u) v |= (int)0x80000000u;
    if (slot < BCAP) csr[d * BCAP + slot] = v;
}

// One wave per dst node, chunk = 16 edges, zero LDS, bf16 z, shared-max
// softmax (neg graph ⊂ full graph, shift invariance -> one running max).
// PROVEN-GOOD STRUCTURE. Allocator-fragile: the speed depends on one flat
// batch of 16 independent loads staying in VGPRs. DO NOT: enlarge the batch
// (r6: 237 µs), branch inside the chunk body (r6), or add LDS/barriers/
// atomics to this kernel (r3: 195 µs).
__global__ __launch_bounds__(256) void k_agg(const int* __restrict__ degarr,
                                             const int* __restrict__ csr,
                                             const unsigned short* __restrict__ z,
                                             const float* __restrict__ el,
                                             const float* __restrict__ er,
                                             const float* __restrict__ bias,
                                             const float* __restrict__ prelu_a,
                                             float* __restrict__ out,
                                             float* __restrict__ expcos) {
    const int lane = threadIdx.x & 63;
    const int wid = threadIdx.x >> 6;
    const int d = (blockIdx.x << 2) + wid;  // grid = NDST/4 exactly

    const int g = NSRC + d;
    const int hl = lane >> 3;
    const int j8 = lane & 7;
    const int rs = d * BCAP;
    const int deg = degarr[d];
    const float erd = er[g * NH + hl];
    const float aslope = prelu_a[0];
    const float NEGINF = -__builtin_inff();

    float mF = NEGINF, lF = 0.f, lN = 0.f;
    float aF0 = 0.f, aF1 = 0.f, aN0 = 0.f, aN1 = 0.f;

    for (int base = 0; base < deg; base += 16) {
        const int j0 = base + j8, j1 = base + 8 + j8;
        int ent0 = (j0 < deg) ? csr[rs + j0] : g;
        int ent1 = (j1 < deg) ? csr[rs + j1] : g;
        unsigned int zr[16];  // bf16x2 per lane per edge-row
#pragma unroll
        for (int jj = 0; jj < 16; ++jj) {
            int entry = __shfl((jj < 8) ? ent0 : ent1, jj & 7, 64);
            zr[jj] = *(const unsigned int*)(z + ((size_t)(entry & 0x7FFFFFFF) << 7) + 2 * lane);
        }
        float e0 = el[(size_t)(ent0 & 0x7FFFFFFF) * NH + hl] + erd;
        float e1 = el[(size_t)(ent1 & 0x7FFFFFFF) * NH + hl] + erd;
        e0 = (e0 >= 0.f) ? e0 : 0.2f * e0;
        e1 = (e1 >= 0.f) ? e1 : 0.2f * e1;
        float ev0 = (j0 < deg) ? e0 : NEGINF;
        float ev1 = (j1 < deg) ? e1 : NEGINF;
        const int fl0 = (j0 < deg) && (ent0 < 0);
        const int fl1 = (j1 < deg) && (ent1 < 0);
        float cm = fmaxf(ev0, ev1);
#pragma unroll
        for (int s = 1; s <= 4; s <<= 1) cm = fmaxf(cm, __shfl_xor(cm, s, 64));
        float nm = fmaxf(mF, cm);
        float sc = (nm == mF) ? 1.f : __expf(mF - nm);
        mF = nm;
        float wf0 = __expf(ev0 - mF);  // 0 for pad slots (mF finite)
        float wf1 = __expf(ev1 - mF);
        lF = lF * sc + wf0 + wf1;
        lN = lN * sc + (fl0 ? wf0 : 0.f) + (fl1 ? wf1 : 0.f);
        float w0 = fl0 ? -wf0 : wf0;  // sign bit = neg-graph membership
        float w1 = fl1 ? -wf1 : wf1;
        aF0 *= sc; aF1 *= sc; aN0 *= sc; aN1 *= sc;
#pragma unroll
        for (int jj = 0; jj < 16; ++jj) {
            float v = __shfl((jj < 8) ? w0 : w1, (lane & 56) | (jj & 7), 64);
            float wf = fabsf(v);
            float wn = (v < 0.f) ? wf : 0.f;
            float zx = __uint_as_float(zr[jj] << 16);
            float zy = __uint_as_float(zr[jj] & 0xffff0000u);
            aF0 = fmaf(wf, zx, aF0);
            aF1 = fmaf(wf, zy, aF1);
            aN0 = fmaf(wn, zx, aN0);
            aN1 = fmaf(wn, zy, aN1);
        }
    }

    // self-loop (in both graphs, shares mF)
    {
        float e = el[g * NH + hl] + erd;
        e = (e >= 0.f) ? e : 0.2f * e;
        float nm = fmaxf(mF, e);
        float sc = (nm == mF) ? 1.f : __expf(mF - nm);
        lF *= sc; lN *= sc;
        aF0 *= sc; aF1 *= sc; aN0 *= sc; aN1 *= sc;
        mF = nm;
        float wf = __expf(e - mF);
        if (j8 == 0) { lF += wf; lN += wf; }  // denom: once per head group
        unsigned int zv = *(const unsigned int*)(z + ((size_t)g << 7) + 2 * lane);
        float zx = __uint_as_float(zv << 16);
        float zy = __uint_as_float(zv & 0xffff0000u);
        aF0 = fmaf(wf, zx, aF0);
        aF1 = fmaf(wf, zy, aF1);
        aN0 = fmaf(wf, zx, aN0);
        aN1 = fmaf(wf, zy, aN1);
    }

    // denominators per head group (reduce over j8 bits)
#pragma unroll
    for (int s = 1; s <= 4; s <<= 1) {
        lF += __shfl_xor(lF, s, 64);
        lN += __shfl_xor(lN, s, 64);
    }
    const int c0 = 2 * lane;
    float b0 = bias[c0], b1 = bias[c0 + 1];
    float rF0 = aF0 / lF + b0, rF1 = aF1 / lF + b1;
    float rN0 = aN0 / lN + b0, rN1 = aN1 / lN + b1;
    rF0 = (rF0 >= 0.f) ? rF0 : aslope * rF0;
    rF1 = (rF1 >= 0.f) ? rF1 : aslope * rF1;
    rN0 = (rN0 >= 0.f) ? rN0 : aslope * rN0;
    rN1 = (rN1 >= 0.f) ? rN1 : aslope * rN1;
    // head mean: sum over heads (bits 3..5), /8
#pragma unroll
    for (int s = 8; s <= 32; s <<= 1) {
        rF0 += __shfl_xor(rF0, s, 64);
        rF1 += __shfl_xor(rF1, s, 64);
        rN0 += __shfl_xor(rN0, s, 64);
        rN1 += __shfl_xor(rN1, s, 64);
    }
    float hF0 = rF0 * 0.125f, hF1 = rF1 * 0.125f;
    float hN0 = rN0 * 0.125f, hN1 = rN1 * 0.125f;
    if (lane < 8) {
        out[1 + d * ND + 2 * lane] = hF0;
        out[1 + d * ND + 2 * lane + 1] = hF1;
    }
    float num = hF0 * hN0 + hF1 * hN1;
    float na = hF0 * hF0 + hF1 * hF1;
    float nb = hN0 * hN0 + hN1 * hN1;
#pragma unroll
    for (int s = 1; s <= 4; s <<= 1) {
        num += __shfl_xor(num, s, 64);
        na += __shfl_xor(na, s, 64);
        nb += __shfl_xor(nb, s, 64);
    }
    if (lane == 0) {
        float cosv = num / (fmaxf(sqrtf(na), 1e-8f) * fmaxf(sqrtf(nb), 1e-8f));
        expcos[d] = __expf(cosv / 0.7f);
    }
}

__global__ __launch_bounds__(1024) void k_loss(const float* __restrict__ expcos,
                                               float* __restrict__ out) {
    __shared__ float sbuf[16];
    float s = 0.f;
    for (int i = threadIdx.x; i < NDST; i += 1024) s += expcos[i];
    for (int sh = 1; sh < 64; sh <<= 1) s += __shfl_xor(s, sh, 64);
    if ((threadIdx.x & 63) == 0) sbuf[threadIdx.x >> 6] = s;
    __syncthreads();
    if (threadIdx.x < 16) {
        float t = sbuf[threadIdx.x];
        for (int sh = 1; sh < 16; sh <<= 1) t += __shfl_xor(t, sh, 16);
        if (threadIdx.x == 0) out[0] = logf(t);
    }
}

extern "C" void kernel_launch(void* const* d_in, const int* in_sizes, int n_in,
                              void* d_out, int out_size, void* d_ws, size_t ws_size,
                              hipStream_t stream) {
    const float* feat = (const float*)d_in[0];
    const float* fc_w = (const float*)d_in[1];
    const float* attn_l = (const float*)d_in[2];
    const float* attn_r = (const float*)d_in[3];
    const float* bias = (const float*)d_in[4];
    const float* prelu_a = (const float*)d_in[5];
    const int* edge_src = (const int*)d_in[6];
    const int* edge_dst = (const int*)d_in[7];
    const int* neg_idx = (const int*)d_in[8];
    float* out = (float*)d_out;

    char* ws = (char*)d_ws;
    int* cursor = (int*)(ws + 0);
    unsigned int* negbits = (unsigned int*)(ws + 80000);
    int* csr = (int*)(ws + 120064);
    float* expcos = (float*)(ws + 5240064);
    unsigned short* z = (unsigned short*)(ws + 5320064);
    float* el = (float*)(ws + 15560064);
    float* er = (float*)(ws + 16840064);
    unsigned short* bt = (unsigned short*)(ws + 18120064);

    hipMemsetAsync(ws, 0, 80000, stream);              // cursor
    hipMemsetAsync(ws + 80000, 0xFF, 40000, stream);   // negbits = all-member
    k_prep<<<64 + (ENEG + 256) / 256, 256, 0, stream>>>(fc_w, neg_idx, bt, negbits);
    k_front<<<625, 256, 0, stream>>>(feat, bt, attn_l, attn_r, z, el, er);
    k_scatter<<<(ETOT + 255) / 256, 256, 0, stream>>>(edge_src, edge_dst,
                                                      negbits, cursor, csr);
    k_agg<<<NDST / 4, 256, 0, stream>>>(cursor, csr, z, el, er, bias, prelu_a,
                                        out, expcos);
    k_loss<<<1, 1024, 0, stream>>>(expcos, out);
}

// Round 11
// 145.367 us; speedup vs baseline: 1.4045x; 1.1110x over previous
//
#include <hip/hip_runtime.h>

#define NSRC 20000
#define NDST 20000
#define NTOT 40000
#define ETOT 320000
#define ENEG 316800
#define NH 8
#define ND 16
#define NHD 128
#define BCAP 64  // fixed bucket capacity per dst (Poisson(16): P(>63) ~ 1e-20)

typedef __bf16 v8bf __attribute__((ext_vector_type(8)));
typedef float v4f __attribute__((ext_vector_type(4)));

// ---------------- workspace layout (bytes) ----------------
// [0, 80000)           cursor/deg (20000 int)   } one memset(0)
// [80000, 120000)      negbits (10000 u32; bit=0 -> edge IS in neg set) }
// [120064, 5240064)    csr buckets (20000 x 64 int; bit31 = in-neg-set)
// [5240064, 5320064)   expcos (20000 f32)
// [5320064, 15560064)  z (40000 x 128 bf16)
// [15560064, 16840064) el (40000 x 8 f32)
// [16840064, 18120064) er (40000 x 8 f32)
// [18120064, 18152832) bt (128 x 128 bf16 = fc_w transposed)

// prep: blocks 0..63 transpose fc_w -> bt (bf16 [n][k]); blocks 64.. set the
// ~3200 NON-member bits (inverted encoding; memset-0 = member). neg_idx is
// SORTED + 99% dense: per-member atomicOr serialized on same-word RMWs
// (r9: 50 µs); the complement is ~3200 scattered atomics (r10: fixed).
__global__ __launch_bounds__(256) void k_prep(const float* __restrict__ B,
                                              const int* __restrict__ neg_idx,
                                              unsigned short* __restrict__ bt,
                                              unsigned int* __restrict__ negbits) {
    const int bid = blockIdx.x;
    if (bid < 64) {  // coalesced read of B, scattered 2B write of bt
        int i = bid * 256 + threadIdx.x;  // 0..16383
        int k = i >> 7, n = i & 127;
        unsigned int u = __float_as_uint(B[i]);
        unsigned int b = (u + 0x7fffu + ((u >> 16) & 1u)) >> 16;  // RNE
        bt[n * 128 + k] = (unsigned short)b;
        return;
    }
    int i = (bid - 64) * 256 + threadIdx.x;  // 0..ENEG
    if (i > ENEG) return;
    int a = (i == 0) ? -1 : neg_idx[i - 1];
    int b = (i == ENEG) ? ETOT : neg_idx[i];
    for (int e = a + 1; e < b; ++e)  // ids NOT in the neg set (total ~3200)
        atomicOr(&negbits[e >> 5], 1u << (e & 31));
}

// Fused: blocks 0..624 = MFMA bf16 GEMM z = feat @ fc_w + el/er epilogue
// (no LDS; B-fragments straight from bt, 32 KB L1/L2-resident); blocks
// 625..1874 = edge bucket-scatter (depends only on k_prep/memset, so it
// overlaps the GEMM on idle CUs instead of serializing as its own node).
__global__ __launch_bounds__(256) void k_front(const float* __restrict__ A,
                                               const unsigned short* __restrict__ bt,
                                               const float* __restrict__ attn_l,
                                               const float* __restrict__ attn_r,
                                               const int* __restrict__ edge_src,
                                               const int* __restrict__ edge_dst,
                                               const unsigned int* __restrict__ negbits,
                                               int* __restrict__ cursor,
                                               int* __restrict__ csr,
                                               unsigned short* __restrict__ z,
                                               float* __restrict__ el,
                                               float* __restrict__ er) {
    const int tid = threadIdx.x;
    const int bid = blockIdx.x;
    if (bid >= 625) {  // ---- scatter blocks (1250 x 256 = ETOT) ----
        int i = (bid - 625) * 256 + tid;
        if (i >= ETOT) return;
        int d = edge_dst[i] - NSRC;
        int slot = atomicAdd(&cursor[d], 1);
        int v = edge_src[i];
        if (!((negbits[i >> 5] >> (i & 31)) & 1u)) v |= (int)0x80000000u;
        if (slot < BCAP) csr[d * BCAP + slot] = v;
        return;
    }
    const int w = tid >> 6, lane = tid & 63;
    const int ml = lane & 15, q = lane >> 4;
    const int gm = bid * 64 + w * 16 + ml;  // this lane's A row (m = lane&15)
    v4f acc[8];
#pragma unroll
    for (int n = 0; n < 8; ++n) acc[n] = (v4f){0.f, 0.f, 0.f, 0.f};
#pragma unroll
    for (int ks = 0; ks < 4; ++ks) {
        const int k0 = ks * 32 + q * 8;  // A[m][k]: k = quad*8 + j
        float4 f0 = *(const float4*)(A + (size_t)gm * 128 + k0);
        float4 f1 = *(const float4*)(A + (size_t)gm * 128 + k0 + 4);
        v8bf av;
        av[0] = (__bf16)f0.x; av[1] = (__bf16)f0.y;
        av[2] = (__bf16)f0.z; av[3] = (__bf16)f0.w;
        av[4] = (__bf16)f1.x; av[5] = (__bf16)f1.y;
        av[6] = (__bf16)f1.z; av[7] = (__bf16)f1.w;
#pragma unroll
        for (int n = 0; n < 8; ++n) {
            v8bf bv = *(const v8bf*)(bt + (size_t)(n * 16 + ml) * 128 + k0);
            acc[n] = __builtin_amdgcn_mfma_f32_16x16x32_bf16(av, bv, acc[n], 0, 0, 0);
        }
    }
    // ---- epilogue: z store (bf16 RNE) + el/er from fp32 accumulators ----
    // C layout: row = q*4 + reg, col = n*16 + ml  (head = n)
    const int rowbase = bid * 64 + w * 16 + q * 4;
#pragma unroll
    for (int n = 0; n < 8; ++n) {
        float alv = attn_l[n * 16 + ml];
        float arv = attn_r[n * 16 + ml];
#pragma unroll
        for (int r = 0; r < 4; ++r) {
            float v = acc[n][r];
            unsigned int u = __float_as_uint(v);
            unsigned int b = (u + 0x7fffu + ((u >> 16) & 1u)) >> 16;  // RNE
            z[(size_t)(rowbase + r) * NHD + n * 16 + ml] = (unsigned short)b;
            float pl = v * alv, pr = v * arv;
#pragma unroll
            for (int s = 1; s <= 8; s <<= 1) {  // reduce 16 cols (lane bits 0..3)
                pl += __shfl_xor(pl, s, 64);
                pr += __shfl_xor(pr, s, 64);
            }
            if (ml == 0) {
                el[(rowbase + r) * NH + n] = pl;
                er[(rowbase + r) * NH + n] = pr;
            }
        }
    }
}

// One wave per dst node, chunk = 16 edges, zero LDS, bf16 z, shared-max
// softmax (neg graph ⊂ full graph, shift invariance -> one running max).
// PROVEN-GOOD STRUCTURE. Allocator-fragile: the speed depends on one flat
// batch of 16 independent loads staying in VGPRs. DO NOT: enlarge the batch
// (r6: 237 µs), branch inside the chunk body (r6), or add LDS/barriers/
// atomics to this kernel (r3: 195 µs).
__global__ __launch_bounds__(256) void k_agg(const int* __restrict__ degarr,
                                             const int* __restrict__ csr,
                                             const unsigned short* __restrict__ z,
                                             const float* __restrict__ el,
                                             const float* __restrict__ er,
                                             const float* __restrict__ bias,
                                             const float* __restrict__ prelu_a,
                                             float* __restrict__ out,
                                             float* __restrict__ expcos) {
    const int lane = threadIdx.x & 63;
    const int wid = threadIdx.x >> 6;
    const int d = (blockIdx.x << 2) + wid;  // grid = NDST/4 exactly

    const int g = NSRC + d;
    const int hl = lane >> 3;
    const int j8 = lane & 7;
    const int rs = d * BCAP;
    const int deg = degarr[d];
    const float erd = er[g * NH + hl];
    const float aslope = prelu_a[0];
    const float NEGINF = -__builtin_inff();

    float mF = NEGINF, lF = 0.f, lN = 0.f;
    float aF0 = 0.f, aF1 = 0.f, aN0 = 0.f, aN1 = 0.f;

    for (int base = 0; base < deg; base += 16) {
        const int j0 = base + j8, j1 = base + 8 + j8;
        int ent0 = (j0 < deg) ? csr[rs + j0] : g;
        int ent1 = (j1 < deg) ? csr[rs + j1] : g;
        unsigned int zr[16];  // bf16x2 per lane per edge-row
#pragma unroll
        for (int jj = 0; jj < 16; ++jj) {
            int entry = __shfl((jj < 8) ? ent0 : ent1, jj & 7, 64);
            zr[jj] = *(const unsigned int*)(z + ((size_t)(entry & 0x7FFFFFFF) << 7) + 2 * lane);
        }
        float e0 = el[(size_t)(ent0 & 0x7FFFFFFF) * NH + hl] + erd;
        float e1 = el[(size_t)(ent1 & 0x7FFFFFFF) * NH + hl] + erd;
        e0 = (e0 >= 0.f) ? e0 : 0.2f * e0;
        e1 = (e1 >= 0.f) ? e1 : 0.2f * e1;
        float ev0 = (j0 < deg) ? e0 : NEGINF;
        float ev1 = (j1 < deg) ? e1 : NEGINF;
        const int fl0 = (j0 < deg) && (ent0 < 0);
        const int fl1 = (j1 < deg) && (ent1 < 0);
        float cm = fmaxf(ev0, ev1);
#pragma unroll
        for (int s = 1; s <= 4; s <<= 1) cm = fmaxf(cm, __shfl_xor(cm, s, 64));
        float nm = fmaxf(mF, cm);
        float sc = (nm == mF) ? 1.f : __expf(mF - nm);
        mF = nm;
        float wf0 = __expf(ev0 - mF);  // 0 for pad slots (mF finite)
        float wf1 = __expf(ev1 - mF);
        lF = lF * sc + wf0 + wf1;
        lN = lN * sc + (fl0 ? wf0 : 0.f) + (fl1 ? wf1 : 0.f);
        float w0 = fl0 ? -wf0 : wf0;  // sign bit = neg-graph membership
        float w1 = fl1 ? -wf1 : wf1;
        aF0 *= sc; aF1 *= sc; aN0 *= sc; aN1 *= sc;
#pragma unroll
        for (int jj = 0; jj < 16; ++jj) {
            float v = __shfl((jj < 8) ? w0 : w1, (lane & 56) | (jj & 7), 64);
            float wf = fabsf(v);
            float wn = (v < 0.f) ? wf : 0.f;
            float zx = __uint_as_float(zr[jj] << 16);
            float zy = __uint_as_float(zr[jj] & 0xffff0000u);
            aF0 = fmaf(wf, zx, aF0);
            aF1 = fmaf(wf, zy, aF1);
            aN0 = fmaf(wn, zx, aN0);
            aN1 = fmaf(wn, zy, aN1);
        }
    }

    // self-loop (in both graphs, shares mF)
    {
        float e = el[g * NH + hl] + erd;
        e = (e >= 0.f) ? e : 0.2f * e;
        float nm = fmaxf(mF, e);
        float sc = (nm == mF) ? 1.f : __expf(mF - nm);
        lF *= sc; lN *= sc;
        aF0 *= sc; aF1 *= sc; aN0 *= sc; aN1 *= sc;
        mF = nm;
        float wf = __expf(e - mF);
        if (j8 == 0) { lF += wf; lN += wf; }  // denom: once per head group
        unsigned int zv = *(const unsigned int*)(z + ((size_t)g << 7) + 2 * lane);
        float zx = __uint_as_float(zv << 16);
        float zy = __uint_as_float(zv & 0xffff0000u);
        aF0 = fmaf(wf, zx, aF0);
        aF1 = fmaf(wf, zy, aF1);
        aN0 = fmaf(wf, zx, aN0);
        aN1 = fmaf(wf, zy, aN1);
    }

    // denominators per head group (reduce over j8 bits)
#pragma unroll
    for (int s = 1; s <= 4; s <<= 1) {
        lF += __shfl_xor(lF, s, 64);
        lN += __shfl_xor(lN, s, 64);
    }
    const int c0 = 2 * lane;
    float b0 = bias[c0], b1 = bias[c0 + 1];
    float rF0 = aF0 / lF + b0, rF1 = aF1 / lF + b1;
    float rN0 = aN0 / lN + b0, rN1 = aN1 / lN + b1;
    rF0 = (rF0 >= 0.f) ? rF0 : aslope * rF0;
    rF1 = (rF1 >= 0.f) ? rF1 : aslope * rF1;
    rN0 = (rN0 >= 0.f) ? rN0 : aslope * rN0;
    rN1 = (rN1 >= 0.f) ? rN1 : aslope * rN1;
    // head mean: sum over heads (bits 3..5), /8
#pragma unroll
    for (int s = 8; s <= 32; s <<= 1) {
        rF0 += __shfl_xor(rF0, s, 64);
        rF1 += __shfl_xor(rF1, s, 64);
        rN0 += __shfl_xor(rN0, s, 64);
        rN1 += __shfl_xor(rN1, s, 64);
    }
    float hF0 = rF0 * 0.125f, hF1 = rF1 * 0.125f;
    float hN0 = rN0 * 0.125f, hN1 = rN1 * 0.125f;
    if (lane < 8) {
        out[1 + d * ND + 2 * lane] = hF0;
        out[1 + d * ND + 2 * lane + 1] = hF1;
    }
    float num = hF0 * hN0 + hF1 * hN1;
    float na = hF0 * hF0 + hF1 * hF1;
    float nb = hN0 * hN0 + hN1 * hN1;
#pragma unroll
    for (int s = 1; s <= 4; s <<= 1) {
        num += __shfl_xor(num, s, 64);
        na += __shfl_xor(na, s, 64);
        nb += __shfl_xor(nb, s, 64);
    }
    if (lane == 0) {
        float cosv = num / (fmaxf(sqrtf(na), 1e-8f) * fmaxf(sqrtf(nb), 1e-8f));
        expcos[d] = __expf(cosv / 0.7f);
    }
}

__global__ __launch_bounds__(1024) void k_loss(const float* __restrict__ expcos,
                                               float* __restrict__ out) {
    __shared__ float sbuf[16];
    float s = 0.f;
    for (int i = threadIdx.x; i < NDST; i += 1024) s += expcos[i];
    for (int sh = 1; sh < 64; sh <<= 1) s += __shfl_xor(s, sh, 64);
    if ((threadIdx.x & 63) == 0) sbuf[threadIdx.x >> 6] = s;
    __syncthreads();
    if (threadIdx.x < 16) {
        float t = sbuf[threadIdx.x];
        for (int sh = 1; sh < 16; sh <<= 1) t += __shfl_xor(t, sh, 16);
        if (threadIdx.x == 0) out[0] = logf(t);
    }
}

extern "C" void kernel_launch(void* const* d_in, const int* in_sizes, int n_in,
                              void* d_out, int out_size, void* d_ws, size_t ws_size,
                              hipStream_t stream) {
    const float* feat = (const float*)d_in[0];
    const float* fc_w = (const float*)d_in[1];
    const float* attn_l = (const float*)d_in[2];
    const float* attn_r = (const float*)d_in[3];
    const float* bias = (const float*)d_in[4];
    const float* prelu_a = (const float*)d_in[5];
    const int* edge_src = (const int*)d_in[6];
    const int* edge_dst = (const int*)d_in[7];
    const int* neg_idx = (const int*)d_in[8];
    float* out = (float*)d_out;

    char* ws = (char*)d_ws;
    int* cursor = (int*)(ws + 0);
    unsigned int* negbits = (unsigned int*)(ws + 80000);
    int* csr = (int*)(ws + 120064);
    float* expcos = (float*)(ws + 5240064);
    unsigned short* z = (unsigned short*)(ws + 5320064);
    float* el = (float*)(ws + 15560064);
    float* er = (float*)(ws + 16840064);
    unsigned short* bt = (unsigned short*)(ws + 18120064);

    hipMemsetAsync(ws, 0, 120000, stream);  // cursor + negbits (0 = member)
    k_prep<<<64 + (ENEG + 256) / 256, 256, 0, stream>>>(fc_w, neg_idx, bt, negbits);
    k_front<<<625 + (ETOT + 255) / 256, 256, 0, stream>>>(
        feat, bt, attn_l, attn_r, edge_src, edge_dst, negbits, cursor, csr,
        z, el, er);
    k_agg<<<NDST / 4, 256, 0, stream>>>(cursor, csr, z, el, er, bias, prelu_a,
                                        out, expcos);
    k_loss<<<1, 1024, 0, stream>>>(expcos, out);
}